// Round 4
// baseline (432.591 us; speedup 1.0000x reference)
//
#include <hip/hip_runtime.h>
#include <hip/hip_bf16.h>

#define EPS 1e-5f

typedef __attribute__((ext_vector_type(8))) short bf16x8;
typedef __attribute__((ext_vector_type(4))) float f32x4;

// ---- async global->LDS, 16B per lane, linear dest (wave-uniform base + lane*16)
__device__ __forceinline__ void gld_lds16(const void* g, void* l) {
    __builtin_amdgcn_global_load_lds(
        (const __attribute__((address_space(1))) unsigned int*)g,
        (__attribute__((address_space(3))) unsigned int*)l, 16, 0, 0);
}

// ---------------- pre-pass: weights [256][256][3][3] f32 -> [256][9][256] bf16
__global__ __launch_bounds__(256) void wt_transpose_bf16(
    const float* __restrict__ w, __hip_bfloat16* __restrict__ wt)
{
    const int co = blockIdx.x;
    const int ci = threadIdx.x;
    const float* wp = w + (size_t)co * 2304 + (size_t)ci * 9;
    __hip_bfloat16* wo = wt + (size_t)co * 2304 + ci;
#pragma unroll
    for (int j = 0; j < 9; ++j)
        wo[(size_t)j * 256] = __float2bfloat16(wp[j]);
}

// ---------------- pre-pass: f32 -> bf16 elementwise (for w_h1)
__global__ __launch_bounds__(256) void f32_to_bf16(
    const float* __restrict__ x, __hip_bfloat16* __restrict__ y, int n)
{
    int i = blockIdx.x * 256 + threadIdx.x;
    if (i < n) y[i] = __float2bfloat16(x[i]);
}

// ---------------- pre-pass: x [B][256][P] f32 -> xt [B][P][256] bf16 (NHWC)
__global__ __launch_bounds__(256) void nchw_to_nhwc_bf16(
    const float* __restrict__ x, __hip_bfloat16* __restrict__ xt, int P)
{
    const int b   = blockIdx.z;
    const int ci0 = blockIdx.y * 32;
    const int p0  = blockIdx.x * 32;
    const int tx  = threadIdx.x & 31, ty = threadIdx.x >> 5; // 32x8
    __shared__ float t[32][33];
    const float* xb = x + ((size_t)b * 256 + ci0) * P;
#pragma unroll
    for (int r = 0; r < 4; ++r) {
        int ci = ty + r * 8;
        int p  = p0 + tx;
        if (p < P) t[ci][tx] = xb[(size_t)ci * P + p];
    }
    __syncthreads();
    __hip_bfloat16* xo = xt + (size_t)b * P * 256 + ci0;
#pragma unroll
    for (int r = 0; r < 4; ++r) {
        int p = p0 + ty + r * 8;
        if (p < P) xo[(size_t)p * 256 + tx] = __float2bfloat16(t[tx][ty + r * 8]);
    }
}

// ---------------- conv3x3 via MFMA implicit GEMM + fused BN+ReLU, NHWC out ----
// M = 256 (co), N = B*POUT (pixels), K = 2304 (256 ci x 9 taps)
// block: 256 thr = 4 waves; tile 128(co) x 128(pix); wave = 64x64; BK=32
// Double-buffered LDS; stage(t+1) issued BEFORE compute(t); one barrier/step.
template<int HIN, int WIN>
__global__ __launch_bounds__(256) void conv3x3_mfma(
    const __hip_bfloat16* __restrict__ xt,  // [B][HIN][WIN][256]
    const __hip_bfloat16* __restrict__ wt,  // [256][9][256]
    const float* __restrict__ g, const float* __restrict__ bb,
    const float* __restrict__ mm_, const float* __restrict__ vv,
    __hip_bfloat16* __restrict__ y)         // NHWC: [B*POUT][256]
{
    constexpr int HOUT = HIN - 2, WOUT = WIN - 2, POUT = HOUT * WOUT;
    const int n0  = blockIdx.x * 128;
    const int co0 = blockIdx.y * 128;
    const int tid = threadIdx.x;
    const int wid = tid >> 6, lane = tid & 63;
    const int wr = wid >> 1, wc = wid & 1;

    // 2 buffers x 128 rows x 32 K, A and B -> 32 KB total
    __shared__ __align__(16) __hip_bfloat16 lA[2 * 128 * 32];
    __shared__ __align__(16) __hip_bfloat16 lB[2 * 128 * 32];

    const int row0 = wid * 16 + (lane >> 2);
    const int row1 = row0 + 64;
    const int seg  = lane & 3;

    const size_t wbase0 = (size_t)(co0 + row0) * 2304 + seg * 8;
    const size_t wbase1 = (size_t)(co0 + row1) * 2304 + seg * 8;

    int n_r0 = n0 + row0;
    int b_r0 = n_r0 / POUT, p_r0 = n_r0 % POUT;
    int oy0 = p_r0 / WOUT, ox0 = p_r0 % WOUT;
    const size_t xbase0 = (((size_t)b_r0 * HIN + oy0) * WIN + ox0) * 256 + seg * 8;
    int n_r1 = n0 + row1;
    int b_r1 = n_r1 / POUT, p_r1 = n_r1 % POUT;
    int oy1 = p_r1 / WOUT, ox1 = p_r1 % WOUT;
    const size_t xbase1 = (((size_t)b_r1 * HIN + oy1) * WIN + ox1) * 256 + seg * 8;

    // stage K-step (c0, j) into buffer sel; each wave covers its 16-row strip
    auto STAGE = [&](int c0, int j, int sel) {
        char* a0 = (char*)lA + sel * 8192 + wid * 1024;
        char* b0 = (char*)lB + sel * 8192 + wid * 1024;
        const int woff = j * 256 + c0;
        gld_lds16(wt + wbase0 + woff, a0);
        gld_lds16(wt + wbase1 + woff, a0 + 4096);
        const int xoff = ((j / 3) * WIN + (j % 3)) * 256 + c0;
        gld_lds16(xt + xbase0 + xoff, b0);
        gld_lds16(xt + xbase1 + xoff, b0 + 4096);
    };

    f32x4 acc[4][4];
#pragma unroll
    for (int i = 0; i < 4; ++i)
#pragma unroll
        for (int j = 0; j < 4; ++j)
            acc[i][j] = f32x4{0.f, 0.f, 0.f, 0.f};

    const int l15 = lane & 15, l16 = lane >> 4;
    const int aoff = (wr * 64 + l15) * 32 + l16 * 8;  // elements within buffer
    const int boff = (wc * 64 + l15) * 32 + l16 * 8;

    STAGE(0, 0, 0);
    __syncthreads();          // vmcnt(0) drain + barrier: buf0 ready
    int cur = 0;

    for (int c0 = 0; c0 < 256; c0 += 32) {
#pragma unroll
        for (int j = 0; j < 9; ++j) {
            // issue next step's loads into the other buffer (fly during MFMA)
            int jn = j + 1, c0n = c0;
            if (jn == 9) { jn = 0; c0n += 32; }
            if (c0n < 256) STAGE(c0n, jn, cur ^ 1);

            const int base = cur * 4096;  // elements
            bf16x8 a[4], b[4];
#pragma unroll
            for (int i = 0; i < 4; ++i)
                a[i] = *reinterpret_cast<const bf16x8*>(&lA[base + aoff + i * 512]);
#pragma unroll
            for (int i = 0; i < 4; ++i)
                b[i] = *reinterpret_cast<const bf16x8*>(&lB[base + boff + i * 512]);
#pragma unroll
            for (int i = 0; i < 4; ++i)
#pragma unroll
                for (int jj = 0; jj < 4; ++jj)
                    acc[i][jj] = __builtin_amdgcn_mfma_f32_16x16x32_bf16(
                        a[i], b[jj], acc[i][jj], 0, 0, 0);

            __syncthreads();  // drains vmcnt (next-step loads) + read-done fence
            cur ^= 1;
        }
    }

    // epilogue: D[m=(lane>>4)*4+r][n=lane&15]; NHWC store y[n][co]
#pragma unroll
    for (int i = 0; i < 4; ++i) {
#pragma unroll
        for (int r = 0; r < 4; ++r) {
            const int co = co0 + wr * 64 + i * 16 + l16 * 4 + r;
            const float sc = g[co] * rsqrtf(vv[co] + EPS);
            const float sh = bb[co] - mm_[co] * sc;
#pragma unroll
            for (int jj = 0; jj < 4; ++jj) {
                const int n = n0 + wc * 64 + jj * 16 + l15;
                const float v = fmaf(acc[i][jj][r], sc, sh);
                y[(size_t)n * 256 + co] = __float2bfloat16(fmaxf(v, 0.f));
            }
        }
    }
}

// ---------------- depthwise xcorr 5x5, NHWC, fully coalesced ----------------
__global__ __launch_bounds__(256) void xcorr_dw_nhwc(
    const __hip_bfloat16* __restrict__ s,  // [B][841][256]
    const __hip_bfloat16* __restrict__ k,  // [B][25][256]
    __hip_bfloat16* __restrict__ f)        // [B][625][256]
{
    const int py = blockIdx.x, b = blockIdx.y, c = threadIdx.x;
    const __hip_bfloat16* sp = s + ((size_t)b * 841) * 256 + c;
    const __hip_bfloat16* kp = k + ((size_t)b * 25) * 256 + c;

    float acc[25];
#pragma unroll
    for (int i = 0; i < 25; ++i) acc[i] = 0.f;

    for (int ky = 0; ky < 5; ++ky) {
        const __hip_bfloat16* srp = sp + (size_t)(py + ky) * 29 * 256;
        float srow[29];
#pragma unroll
        for (int rx = 0; rx < 29; ++rx) srow[rx] = __bfloat162float(srp[(size_t)rx * 256]);
#pragma unroll
        for (int kx = 0; kx < 5; ++kx) {
            const float kv = __bfloat162float(kp[(size_t)(ky * 5 + kx) * 256]);
#pragma unroll
            for (int px = 0; px < 25; ++px)
                acc[px] = fmaf(srow[px + kx], kv, acc[px]);
        }
    }

    __hip_bfloat16* fp = f + ((size_t)b * 625 + (size_t)py * 25) * 256 + c;
#pragma unroll
    for (int px = 0; px < 25; ++px) fp[(size_t)px * 256] = __float2bfloat16(acc[px]);
}

// ---------------- head layer 1: 1x1 conv via MFMA + BN + ReLU, NHWC ----------
// GEMM: M=256(co), N=80000(pix), K=256(ci); double-buffered like conv
__global__ __launch_bounds__(256) void head1_mfma(
    const __hip_bfloat16* __restrict__ f,   // [N][256]
    const __hip_bfloat16* __restrict__ w1,  // [256][256] bf16
    const float* __restrict__ g, const float* __restrict__ bb,
    const float* __restrict__ mm_, const float* __restrict__ vv,
    __hip_bfloat16* __restrict__ h)         // [N][256]
{
    const int n0  = blockIdx.x * 128;
    const int co0 = blockIdx.y * 128;
    const int tid = threadIdx.x;
    const int wid = tid >> 6, lane = tid & 63;
    const int wr = wid >> 1, wc = wid & 1;

    __shared__ __align__(16) __hip_bfloat16 lA[2 * 128 * 32];
    __shared__ __align__(16) __hip_bfloat16 lB[2 * 128 * 32];

    const int row0 = wid * 16 + (lane >> 2);
    const int row1 = row0 + 64;
    const int seg  = lane & 3;

    const size_t wbase0 = (size_t)(co0 + row0) * 256 + seg * 8;
    const size_t wbase1 = (size_t)(co0 + row1) * 256 + seg * 8;
    const size_t xbase0 = (size_t)(n0 + row0) * 256 + seg * 8;
    const size_t xbase1 = (size_t)(n0 + row1) * 256 + seg * 8;

    auto STAGE = [&](int c0, int sel) {
        char* a0 = (char*)lA + sel * 8192 + wid * 1024;
        char* b0 = (char*)lB + sel * 8192 + wid * 1024;
        gld_lds16(w1 + wbase0 + c0, a0);
        gld_lds16(w1 + wbase1 + c0, a0 + 4096);
        gld_lds16(f + xbase0 + c0, b0);
        gld_lds16(f + xbase1 + c0, b0 + 4096);
    };

    f32x4 acc[4][4];
#pragma unroll
    for (int i = 0; i < 4; ++i)
#pragma unroll
        for (int j = 0; j < 4; ++j)
            acc[i][j] = f32x4{0.f, 0.f, 0.f, 0.f};

    const int l15 = lane & 15, l16 = lane >> 4;
    const int aoff = (wr * 64 + l15) * 32 + l16 * 8;
    const int boff = (wc * 64 + l15) * 32 + l16 * 8;

    STAGE(0, 0);
    __syncthreads();
    int cur = 0;

    for (int c0 = 0; c0 < 256; c0 += 32) {
        if (c0 + 32 < 256) STAGE(c0 + 32, cur ^ 1);

        const int base = cur * 4096;
        bf16x8 a[4], b[4];
#pragma unroll
        for (int i = 0; i < 4; ++i)
            a[i] = *reinterpret_cast<const bf16x8*>(&lA[base + aoff + i * 512]);
#pragma unroll
        for (int i = 0; i < 4; ++i)
            b[i] = *reinterpret_cast<const bf16x8*>(&lB[base + boff + i * 512]);
#pragma unroll
        for (int i = 0; i < 4; ++i)
#pragma unroll
            for (int jj = 0; jj < 4; ++jj)
                acc[i][jj] = __builtin_amdgcn_mfma_f32_16x16x32_bf16(
                    a[i], b[jj], acc[i][jj], 0, 0, 0);

        __syncthreads();
        cur ^= 1;
    }

#pragma unroll
    for (int i = 0; i < 4; ++i) {
#pragma unroll
        for (int r = 0; r < 4; ++r) {
            const int co = co0 + wr * 64 + i * 16 + l16 * 4 + r;
            const float sc = g[co] * rsqrtf(vv[co] + EPS);
            const float sh = bb[co] - mm_[co] * sc;
#pragma unroll
            for (int jj = 0; jj < 4; ++jj) {
                const int n = n0 + wc * 64 + jj * 16 + l15;
                const float v = fmaf(acc[i][jj][r], sc, sh);
                h[(size_t)n * 256 + co] = __float2bfloat16(fmaxf(v, 0.f));
            }
        }
    }
}

// ---------------- head layer 2: 1x1 conv (256 -> 10) + bias, NCHW out --------
__global__ __launch_bounds__(256) void head2(
    const __hip_bfloat16* __restrict__ h,  // [N][256]
    const float* __restrict__ w2,          // [10][256]
    const float* __restrict__ b2,          // [10]
    float* __restrict__ out)               // [B][10][25][25]
{
    const int py = blockIdx.x, b = blockIdx.y;
    __shared__ __hip_bfloat16 lh[25][258];
    __shared__ float lw[10][256];

    const __hip_bfloat16* hp = h + ((size_t)b * 625 + (size_t)py * 25) * 256;
    for (int i = threadIdx.x; i < 25 * 256; i += 256) {
        int px = i >> 8, c = i & 255;
        lh[px][c] = hp[i];
    }
    for (int i = threadIdx.x; i < 10 * 256; i += 256)
        lw[i >> 8][i & 255] = w2[i];
    __syncthreads();

    if (threadIdx.x < 250) {
        const int o = threadIdx.x / 25, px = threadIdx.x % 25;
        float a = b2[o];
        for (int c = 0; c < 256; ++c)
            a = fmaf(__bfloat162float(lh[px][c]), lw[o][c], a);
        out[(((size_t)b * 10 + o) * 25 + py) * 25 + px] = a;
    }
}

extern "C" void kernel_launch(void* const* d_in, const int* in_sizes, int n_in,
                              void* d_out, int out_size, void* d_ws, size_t ws_size,
                              hipStream_t stream) {
    const float* kernel = (const float*)d_in[0];   // [128,256,7,7]
    const float* search = (const float*)d_in[1];   // [128,256,31,31]
    const float* w_ck   = (const float*)d_in[2];
    const float* g1 = (const float*)d_in[3];
    const float* b1 = (const float*)d_in[4];
    const float* m1 = (const float*)d_in[5];
    const float* v1 = (const float*)d_in[6];
    const float* w_cs   = (const float*)d_in[7];
    const float* g2 = (const float*)d_in[8];
    const float* b2 = (const float*)d_in[9];
    const float* m2 = (const float*)d_in[10];
    const float* v2 = (const float*)d_in[11];
    const float* w_h1   = (const float*)d_in[12];
    const float* g3 = (const float*)d_in[13];
    const float* b3 = (const float*)d_in[14];
    const float* m3 = (const float*)d_in[15];
    const float* v3 = (const float*)d_in[16];
    const float* w_h2   = (const float*)d_in[17];
    const float* b_h2   = (const float*)d_in[18];

    float* out = (float*)d_out;

    // ws layout (bf16 elements):
    //  y1    [128*25*256]  NHWC @ 0         (819200)
    //  y2    [128*841*256] NHWC @ 819200    (27557888) -> 28377088
    //  wt_ck [256*9*256]        @ 28377088  (589824)   -> 28966912
    //  wt_cs [256*9*256]        @ 28966912  (589824)   -> 29556736
    //  wh1   [256*256]          @ 29556736  (65536)    -> 29622272
    //  xt_k  [128*49*256]       @ 29622272  (1605632)  -> 31227904
    //  xt_s  [128*961*256]      @ 31227904  (31490048) -> 62717952 (125.4 MB)
    //  feat  [80000*256]   NHWC @ 29622272  (reuses xt region after convs)
    //  h     [80000*256]   NHWC @ 819200    (reuses y2 after xcorr)
    __hip_bfloat16* ws = (__hip_bfloat16*)d_ws;
    __hip_bfloat16* y1    = ws;
    __hip_bfloat16* y2    = ws + (size_t)819200;
    __hip_bfloat16* wt_ck = ws + (size_t)28377088;
    __hip_bfloat16* wt_cs = ws + (size_t)28966912;
    __hip_bfloat16* wh1   = ws + (size_t)29556736;
    __hip_bfloat16* xt_k  = ws + (size_t)29622272;
    __hip_bfloat16* xt_s  = ws + (size_t)31227904;
    __hip_bfloat16* feat  = ws + (size_t)29622272;
    __hip_bfloat16* h     = ws + (size_t)819200;

    (void)in_sizes; (void)n_in; (void)out_size; (void)ws_size;

    // pre-passes
    wt_transpose_bf16<<<256, 256, 0, stream>>>(w_ck, wt_ck);
    wt_transpose_bf16<<<256, 256, 0, stream>>>(w_cs, wt_cs);
    f32_to_bf16<<<256, 256, 0, stream>>>(w_h1, wh1, 65536);
    nchw_to_nhwc_bf16<<<dim3(2, 8, 128), 256, 0, stream>>>(kernel, xt_k, 49);
    nchw_to_nhwc_bf16<<<dim3(31, 8, 128), 256, 0, stream>>>(search, xt_s, 961);

    // convs (MFMA implicit GEMM), NHWC outputs
    conv3x3_mfma<7, 7><<<dim3(25, 2), 256, 0, stream>>>(
        xt_k, wt_ck, g1, b1, m1, v1, y1);
    conv3x3_mfma<31, 31><<<dim3(841, 2), 256, 0, stream>>>(
        xt_s, wt_cs, g2, b2, m2, v2, y2);

    // depthwise xcorr -> feat NHWC
    xcorr_dw_nhwc<<<dim3(25, 128), 256, 0, stream>>>(y2, y1, feat);

    // head
    head1_mfma<<<dim3(625, 2), 256, 0, stream>>>(feat, wh1, g3, b3, m3, v3, h);
    head2<<<dim3(25, 128), 256, 0, stream>>>(h, w_h2, b_h2, out);
}

// Round 5
// 372.881 us; speedup vs baseline: 1.1601x; 1.1601x over previous
//
#include <hip/hip_runtime.h>
#include <hip/hip_bf16.h>

#define EPS 1e-5f

typedef __attribute__((ext_vector_type(8))) short bf16x8;
typedef __attribute__((ext_vector_type(4))) float f32x4;

#define WAITVM8 asm volatile("s_waitcnt vmcnt(8)" ::: "memory")
#define WAITVM4 asm volatile("s_waitcnt vmcnt(4)" ::: "memory")
#define WAITVM0 asm volatile("s_waitcnt vmcnt(0)" ::: "memory")
#define BAR()   __builtin_amdgcn_s_barrier()

// ---- async global->LDS, 16B per lane, linear dest (wave-uniform base + lane*16)
__device__ __forceinline__ void gld_lds16(const void* g, void* l) {
    __builtin_amdgcn_global_load_lds(
        (const __attribute__((address_space(1))) unsigned int*)g,
        (__attribute__((address_space(3))) unsigned int*)l, 16, 0, 0);
}

// ---------------- pre-pass: weights [256][256][3][3] f32 -> [256][9][256] bf16
__global__ __launch_bounds__(256) void wt_transpose_bf16(
    const float* __restrict__ w, __hip_bfloat16* __restrict__ wt)
{
    const int co = blockIdx.x;
    const int ci = threadIdx.x;
    const float* wp = w + (size_t)co * 2304 + (size_t)ci * 9;
    __hip_bfloat16* wo = wt + (size_t)co * 2304 + ci;
#pragma unroll
    for (int j = 0; j < 9; ++j)
        wo[(size_t)j * 256] = __float2bfloat16(wp[j]);
}

// ---------------- pre-pass: f32 -> bf16 elementwise (for w_h1)
__global__ __launch_bounds__(256) void f32_to_bf16(
    const float* __restrict__ x, __hip_bfloat16* __restrict__ y, int n)
{
    int i = blockIdx.x * 256 + threadIdx.x;
    if (i < n) y[i] = __float2bfloat16(x[i]);
}

// ---------------- pre-pass: x [B][256][P] f32 -> xt [B][P][256] bf16 (NHWC)
__global__ __launch_bounds__(256) void nchw_to_nhwc_bf16(
    const float* __restrict__ x, __hip_bfloat16* __restrict__ xt, int P)
{
    const int b   = blockIdx.z;
    const int ci0 = blockIdx.y * 32;
    const int p0  = blockIdx.x * 32;
    const int tx  = threadIdx.x & 31, ty = threadIdx.x >> 5; // 32x8
    __shared__ float t[32][33];
    const float* xb = x + ((size_t)b * 256 + ci0) * P;
#pragma unroll
    for (int r = 0; r < 4; ++r) {
        int ci = ty + r * 8;
        int p  = p0 + tx;
        if (p < P) t[ci][tx] = xb[(size_t)ci * P + p];
    }
    __syncthreads();
    __hip_bfloat16* xo = xt + (size_t)b * P * 256 + ci0;
#pragma unroll
    for (int r = 0; r < 4; ++r) {
        int p = p0 + ty + r * 8;
        if (p < P) xo[(size_t)p * 256 + tx] = __float2bfloat16(t[tx][ty + r * 8]);
    }
}

// ---------------- conv3x3 via MFMA implicit GEMM + fused BN+ReLU, NHWC out ----
// M = 256 (co), N = B*POUT (pixels), K = 2304 (256 ci x 9 taps)
// tile 128x128, 4 waves, BK=32. Counted-vmcnt pipeline: 4 LDS buffers,
// depth-3 prefetch, raw s_barrier, ONE barrier per K-step, never vmcnt(0)
// in the main loop (T3+T4, m201/m218 recipe).
template<int HIN, int WIN>
__global__ __launch_bounds__(256) void conv3x3_mfma(
    const __hip_bfloat16* __restrict__ xt,  // [B][HIN][WIN][256]
    const __hip_bfloat16* __restrict__ wt,  // [256][9][256]
    const float* __restrict__ g, const float* __restrict__ bb,
    const float* __restrict__ mm_, const float* __restrict__ vv,
    __hip_bfloat16* __restrict__ y)         // NHWC: [B*POUT][256]
{
    constexpr int HOUT = HIN - 2, WOUT = WIN - 2, POUT = HOUT * WOUT;
    const int n0  = blockIdx.x * 128;
    const int co0 = blockIdx.y * 128;
    const int tid = threadIdx.x;
    const int wid = tid >> 6, lane = tid & 63;
    const int wr = wid >> 1, wc = wid & 1;

    // 4 buffers x (A 8KB + B 8KB) = 64 KB
    __shared__ __align__(16) __hip_bfloat16 lA[4 * 4096];
    __shared__ __align__(16) __hip_bfloat16 lB[4 * 4096];

    const int row0 = wid * 16 + (lane >> 2);
    const int row1 = row0 + 64;
    const int seg  = lane & 3;

    const size_t wbase0 = (size_t)(co0 + row0) * 2304 + seg * 8;
    const size_t wbase1 = (size_t)(co0 + row1) * 2304 + seg * 8;

    int n_r0 = n0 + row0;
    int b_r0 = n_r0 / POUT, p_r0 = n_r0 % POUT;
    int oy0 = p_r0 / WOUT, ox0 = p_r0 % WOUT;
    const size_t xbase0 = (((size_t)b_r0 * HIN + oy0) * WIN + ox0) * 256 + seg * 8;
    int n_r1 = n0 + row1;
    int b_r1 = n_r1 / POUT, p_r1 = n_r1 % POUT;
    int oy1 = p_r1 / WOUT, ox1 = p_r1 % WOUT;
    const size_t xbase1 = (((size_t)b_r1 * HIN + oy1) * WIN + ox1) * 256 + seg * 8;

    // stage K-step (c0, j) into buffer sel (4 gld instrs -> vmcnt +4)
    auto STAGE = [&](int c0, int j, int sel) {
        char* a0 = (char*)lA + sel * 8192 + wid * 1024;
        char* b0 = (char*)lB + sel * 8192 + wid * 1024;
        const int woff = j * 256 + c0;
        gld_lds16(wt + wbase0 + woff, a0);
        gld_lds16(wt + wbase1 + woff, a0 + 4096);
        const int xoff = ((j / 3) * WIN + (j % 3)) * 256 + c0;
        gld_lds16(xt + xbase0 + xoff, b0);
        gld_lds16(xt + xbase1 + xoff, b0 + 4096);
    };

    f32x4 acc[4][4];
#pragma unroll
    for (int i = 0; i < 4; ++i)
#pragma unroll
        for (int j = 0; j < 4; ++j)
            acc[i][j] = f32x4{0.f, 0.f, 0.f, 0.f};

    const int l15 = lane & 15, l16 = lane >> 4;
    const int aoff = (wr * 64 + l15) * 32 + l16 * 8;  // elems within buffer
    const int boff = (wc * 64 + l15) * 32 + l16 * 8;

    // compute from buffer sel: 8 ds_read_b128 + 16 MFMA (every read feeds MFMA,
    // so the compiler's lgkmcnt drain before the last MFMA fences the reads)
    auto COMPUTE = [&](int sel) {
        const int base = sel * 4096;
        bf16x8 a[4], b[4];
#pragma unroll
        for (int i = 0; i < 4; ++i)
            a[i] = *reinterpret_cast<const bf16x8*>(&lA[base + aoff + i * 512]);
#pragma unroll
        for (int i = 0; i < 4; ++i)
            b[i] = *reinterpret_cast<const bf16x8*>(&lB[base + boff + i * 512]);
#pragma unroll
        for (int i = 0; i < 4; ++i)
#pragma unroll
            for (int jj = 0; jj < 4; ++jj)
                acc[i][jj] = __builtin_amdgcn_mfma_f32_16x16x32_bf16(
                    a[i], b[jj], acc[i][jj], 0, 0, 0);
    };

    // prologue: stage steps 0,1,2 (12 gld in flight)
    STAGE(0, 0, 0);
    STAGE(0, 1, 1);
    STAGE(0, 2, 2);
    int c0s = 0, js = 3;  // stage cursor for step t+3

    // main loop: t = 0..67  (72 K-steps total; tail peeled)
    for (int tt = 0; tt < 17; ++tt) {
#pragma unroll
        for (int u = 0; u < 4; ++u) {
            WAITVM8;       // stage(t) complete; stages t+1,t+2 stay in flight
            BAR();
            STAGE(c0s, js, (u + 3) & 3);  // step t+3 -> buf (t+3)%4
            ++js; if (js == 9) { js = 0; c0s += 32; }
            COMPUTE(u);
        }
    }
    // tail: t = 68,69,70,71 (u = 0,1,2,3)
    WAITVM8; BAR(); STAGE(c0s, js, 3); COMPUTE(0);  // t=68 stages step 71
    WAITVM8; BAR(); COMPUTE(1);                     // t=69 (steps 70,71 in flight)
    WAITVM4; BAR(); COMPUTE(2);                     // t=70
    WAITVM0; BAR(); COMPUTE(3);                     // t=71

    // epilogue: D[m=(lane>>4)*4+r][n=lane&15]; NHWC store y[n][co]
#pragma unroll
    for (int i = 0; i < 4; ++i) {
#pragma unroll
        for (int r = 0; r < 4; ++r) {
            const int co = co0 + wr * 64 + i * 16 + l16 * 4 + r;
            const float sc = g[co] * rsqrtf(vv[co] + EPS);
            const float sh = bb[co] - mm_[co] * sc;
#pragma unroll
            for (int jj = 0; jj < 4; ++jj) {
                const int n = n0 + wc * 64 + jj * 16 + l15;
                const float v = fmaf(acc[i][jj][r], sc, sh);
                y[(size_t)n * 256 + co] = __float2bfloat16(fmaxf(v, 0.f));
            }
        }
    }
}

// ---------------- depthwise xcorr 5x5, NHWC, fully coalesced ----------------
__global__ __launch_bounds__(256) void xcorr_dw_nhwc(
    const __hip_bfloat16* __restrict__ s,  // [B][841][256]
    const __hip_bfloat16* __restrict__ k,  // [B][25][256]
    __hip_bfloat16* __restrict__ f)        // [B][625][256]
{
    const int py = blockIdx.x, b = blockIdx.y, c = threadIdx.x;
    const __hip_bfloat16* sp = s + ((size_t)b * 841) * 256 + c;
    const __hip_bfloat16* kp = k + ((size_t)b * 25) * 256 + c;

    float acc[25];
#pragma unroll
    for (int i = 0; i < 25; ++i) acc[i] = 0.f;

    for (int ky = 0; ky < 5; ++ky) {
        const __hip_bfloat16* srp = sp + (size_t)(py + ky) * 29 * 256;
        float srow[29];
#pragma unroll
        for (int rx = 0; rx < 29; ++rx) srow[rx] = __bfloat162float(srp[(size_t)rx * 256]);
#pragma unroll
        for (int kx = 0; kx < 5; ++kx) {
            const float kv = __bfloat162float(kp[(size_t)(ky * 5 + kx) * 256]);
#pragma unroll
            for (int px = 0; px < 25; ++px)
                acc[px] = fmaf(srow[px + kx], kv, acc[px]);
        }
    }

    __hip_bfloat16* fp = f + ((size_t)b * 625 + (size_t)py * 25) * 256 + c;
#pragma unroll
    for (int px = 0; px < 25; ++px) fp[(size_t)px * 256] = __float2bfloat16(acc[px]);
}

// ---------------- head layer 1: 1x1 conv via MFMA + BN + ReLU, NHWC ----------
// GEMM: M=256(co), N=80000(pix), K=256(ci); same counted-vmcnt pipeline,
// 8 K-steps straight-line unrolled.
__global__ __launch_bounds__(256) void head1_mfma(
    const __hip_bfloat16* __restrict__ f,   // [N][256]
    const __hip_bfloat16* __restrict__ w1,  // [256][256] bf16
    const float* __restrict__ g, const float* __restrict__ bb,
    const float* __restrict__ mm_, const float* __restrict__ vv,
    __hip_bfloat16* __restrict__ h)         // [N][256]
{
    const int n0  = blockIdx.x * 128;
    const int co0 = blockIdx.y * 128;
    const int tid = threadIdx.x;
    const int wid = tid >> 6, lane = tid & 63;
    const int wr = wid >> 1, wc = wid & 1;

    __shared__ __align__(16) __hip_bfloat16 lA[4 * 4096];
    __shared__ __align__(16) __hip_bfloat16 lB[4 * 4096];

    const int row0 = wid * 16 + (lane >> 2);
    const int row1 = row0 + 64;
    const int seg  = lane & 3;

    const size_t wbase0 = (size_t)(co0 + row0) * 256 + seg * 8;
    const size_t wbase1 = (size_t)(co0 + row1) * 256 + seg * 8;
    const size_t xbase0 = (size_t)(n0 + row0) * 256 + seg * 8;
    const size_t xbase1 = (size_t)(n0 + row1) * 256 + seg * 8;

    auto STAGE = [&](int c0, int sel) {
        char* a0 = (char*)lA + sel * 8192 + wid * 1024;
        char* b0 = (char*)lB + sel * 8192 + wid * 1024;
        gld_lds16(w1 + wbase0 + c0, a0);
        gld_lds16(w1 + wbase1 + c0, a0 + 4096);
        gld_lds16(f + xbase0 + c0, b0);
        gld_lds16(f + xbase1 + c0, b0 + 4096);
    };

    f32x4 acc[4][4];
#pragma unroll
    for (int i = 0; i < 4; ++i)
#pragma unroll
        for (int j = 0; j < 4; ++j)
            acc[i][j] = f32x4{0.f, 0.f, 0.f, 0.f};

    const int l15 = lane & 15, l16 = lane >> 4;
    const int aoff = (wr * 64 + l15) * 32 + l16 * 8;
    const int boff = (wc * 64 + l15) * 32 + l16 * 8;

    auto COMPUTE = [&](int sel) {
        const int base = sel * 4096;
        bf16x8 a[4], b[4];
#pragma unroll
        for (int i = 0; i < 4; ++i)
            a[i] = *reinterpret_cast<const bf16x8*>(&lA[base + aoff + i * 512]);
#pragma unroll
        for (int i = 0; i < 4; ++i)
            b[i] = *reinterpret_cast<const bf16x8*>(&lB[base + boff + i * 512]);
#pragma unroll
        for (int i = 0; i < 4; ++i)
#pragma unroll
            for (int jj = 0; jj < 4; ++jj)
                acc[i][jj] = __builtin_amdgcn_mfma_f32_16x16x32_bf16(
                    a[i], b[jj], acc[i][jj], 0, 0, 0);
    };

    STAGE(0, 0); STAGE(32, 1); STAGE(64, 2);          // steps 0,1,2
    WAITVM8; BAR(); STAGE(96,  3); COMPUTE(0);        // t=0
    WAITVM8; BAR(); STAGE(128, 0); COMPUTE(1);        // t=1
    WAITVM8; BAR(); STAGE(160, 1); COMPUTE(2);        // t=2
    WAITVM8; BAR(); STAGE(192, 2); COMPUTE(3);        // t=3
    WAITVM8; BAR(); STAGE(224, 3); COMPUTE(0);        // t=4
    WAITVM8; BAR(); COMPUTE(1);                       // t=5 (6,7 in flight)
    WAITVM4; BAR(); COMPUTE(2);                       // t=6
    WAITVM0; BAR(); COMPUTE(3);                       // t=7

#pragma unroll
    for (int i = 0; i < 4; ++i) {
#pragma unroll
        for (int r = 0; r < 4; ++r) {
            const int co = co0 + wr * 64 + i * 16 + l16 * 4 + r;
            const float sc = g[co] * rsqrtf(vv[co] + EPS);
            const float sh = bb[co] - mm_[co] * sc;
#pragma unroll
            for (int jj = 0; jj < 4; ++jj) {
                const int n = n0 + wc * 64 + jj * 16 + l15;
                const float v = fmaf(acc[i][jj][r], sc, sh);
                h[(size_t)n * 256 + co] = __float2bfloat16(fmaxf(v, 0.f));
            }
        }
    }
}

// ---------------- head layer 2: 1x1 conv (256 -> 10) + bias, NCHW out --------
__global__ __launch_bounds__(256) void head2(
    const __hip_bfloat16* __restrict__ h,  // [N][256]
    const float* __restrict__ w2,          // [10][256]
    const float* __restrict__ b2,          // [10]
    float* __restrict__ out)               // [B][10][25][25]
{
    const int py = blockIdx.x, b = blockIdx.y;
    __shared__ __hip_bfloat16 lh[25][258];
    __shared__ float lw[10][256];

    const __hip_bfloat16* hp = h + ((size_t)b * 625 + (size_t)py * 25) * 256;
    for (int i = threadIdx.x; i < 25 * 256; i += 256) {
        int px = i >> 8, c = i & 255;
        lh[px][c] = hp[i];
    }
    for (int i = threadIdx.x; i < 10 * 256; i += 256)
        lw[i >> 8][i & 255] = w2[i];
    __syncthreads();

    if (threadIdx.x < 250) {
        const int o = threadIdx.x / 25, px = threadIdx.x % 25;
        float a = b2[o];
        for (int c = 0; c < 256; ++c)
            a = fmaf(__bfloat162float(lh[px][c]), lw[o][c], a);
        out[(((size_t)b * 10 + o) * 25 + py) * 25 + px] = a;
    }
}

extern "C" void kernel_launch(void* const* d_in, const int* in_sizes, int n_in,
                              void* d_out, int out_size, void* d_ws, size_t ws_size,
                              hipStream_t stream) {
    const float* kernel = (const float*)d_in[0];   // [128,256,7,7]
    const float* search = (const float*)d_in[1];   // [128,256,31,31]
    const float* w_ck   = (const float*)d_in[2];
    const float* g1 = (const float*)d_in[3];
    const float* b1 = (const float*)d_in[4];
    const float* m1 = (const float*)d_in[5];
    const float* v1 = (const float*)d_in[6];
    const float* w_cs   = (const float*)d_in[7];
    const float* g2 = (const float*)d_in[8];
    const float* b2 = (const float*)d_in[9];
    const float* m2 = (const float*)d_in[10];
    const float* v2 = (const float*)d_in[11];
    const float* w_h1   = (const float*)d_in[12];
    const float* g3 = (const float*)d_in[13];
    const float* b3 = (const float*)d_in[14];
    const float* m3 = (const float*)d_in[15];
    const float* v3 = (const float*)d_in[16];
    const float* w_h2   = (const float*)d_in[17];
    const float* b_h2   = (const float*)d_in[18];

    float* out = (float*)d_out;

    // ws layout (bf16 elements):
    //  y1    [128*25*256]  NHWC @ 0         (819200)
    //  y2    [128*841*256] NHWC @ 819200    (27557888) -> 28377088
    //  wt_ck [256*9*256]        @ 28377088  (589824)   -> 28966912
    //  wt_cs [256*9*256]        @ 28966912  (589824)   -> 29556736
    //  wh1   [256*256]          @ 29556736  (65536)    -> 29622272
    //  xt_k  [128*49*256]       @ 29622272  (1605632)  -> 31227904
    //  xt_s  [128*961*256]      @ 31227904  (31490048) -> 62717952 (125.4 MB)
    //  feat  [80000*256]   NHWC @ 29622272  (reuses xt region after convs)
    //  h     [80000*256]   NHWC @ 819200    (reuses y2 after xcorr)
    __hip_bfloat16* ws = (__hip_bfloat16*)d_ws;
    __hip_bfloat16* y1    = ws;
    __hip_bfloat16* y2    = ws + (size_t)819200;
    __hip_bfloat16* wt_ck = ws + (size_t)28377088;
    __hip_bfloat16* wt_cs = ws + (size_t)28966912;
    __hip_bfloat16* wh1   = ws + (size_t)29556736;
    __hip_bfloat16* xt_k  = ws + (size_t)29622272;
    __hip_bfloat16* xt_s  = ws + (size_t)31227904;
    __hip_bfloat16* feat  = ws + (size_t)29622272;
    __hip_bfloat16* h     = ws + (size_t)819200;

    (void)in_sizes; (void)n_in; (void)out_size; (void)ws_size;

    // pre-passes
    wt_transpose_bf16<<<256, 256, 0, stream>>>(w_ck, wt_ck);
    wt_transpose_bf16<<<256, 256, 0, stream>>>(w_cs, wt_cs);
    f32_to_bf16<<<256, 256, 0, stream>>>(w_h1, wh1, 65536);
    nchw_to_nhwc_bf16<<<dim3(2, 8, 128), 256, 0, stream>>>(kernel, xt_k, 49);
    nchw_to_nhwc_bf16<<<dim3(31, 8, 128), 256, 0, stream>>>(search, xt_s, 961);

    // convs (MFMA implicit GEMM), NHWC outputs
    conv3x3_mfma<7, 7><<<dim3(25, 2), 256, 0, stream>>>(
        xt_k, wt_ck, g1, b1, m1, v1, y1);
    conv3x3_mfma<31, 31><<<dim3(841, 2), 256, 0, stream>>>(
        xt_s, wt_cs, g2, b2, m2, v2, y2);

    // depthwise xcorr -> feat NHWC
    xcorr_dw_nhwc<<<dim3(25, 128), 256, 0, stream>>>(y2, y1, feat);

    // head
    head1_mfma<<<dim3(625, 2), 256, 0, stream>>>(feat, wh1, g3, b3, m3, v3, h);
    head2<<<dim3(25, 128), 256, 0, stream>>>(h, w_h2, b_h2, out);
}